// Round 2
// baseline (922.647 us; speedup 1.0000x reference)
//
#include <hip/hip_runtime.h>
#include <cstdint>
#include <cstddef>

#define HID 512
#define BATCH 4096
#define T_STEPS 20

typedef unsigned short ushort_t;
typedef __attribute__((ext_vector_type(8))) __bf16 bf16x8;
typedef __attribute__((ext_vector_type(4))) float f32x4;

typedef __attribute__((address_space(1))) void gvoid;
typedef __attribute__((address_space(3))) void lvoid;

// fp32 -> bf16 round-to-nearest-even (finite inputs only)
__device__ __forceinline__ unsigned short f2bf(float f) {
  unsigned int u = __float_as_uint(f);
  u += 0x7FFFu + ((u >> 16) & 1u);
  return (unsigned short)(u >> 16);
}

__device__ __forceinline__ float wave_max(float v) {
#pragma unroll
  for (int off = 32; off > 0; off >>= 1) v = fmaxf(v, __shfl_xor(v, off));
  return v;
}
__device__ __forceinline__ float wave_sum(float v) {
#pragma unroll
  for (int off = 32; off > 0; off >>= 1) v += __shfl_xor(v, off);
  return v;
}

// async global->LDS, 16B per lane; lds base must be wave-uniform (HW adds lane*16)
__device__ __forceinline__ void load_lds16(const void* g, void* l) {
  __builtin_amdgcn_global_load_lds((gvoid*)g, (lvoid*)l, 16, 0, 0);
}

// ---------------------------------------------------------------------------
// Kernel A: dh[4096,512] = act( zb[4096,512] @ Wcat2[1536,512]^T )
// Wcat2 packed columns: group of 48 = [16 i | 16 g | 16 o] for h-block of 16.
// Tile 128x96 (BK=32), 256 threads = 2x2 waves, wave tile 64x48 (FM=4, FN=3).
// Within a wave, j=0/1/2 are gates i/g/o for the SAME h columns -> epilogue act.
// ---------------------------------------------------------------------------
__global__ __launch_bounds__(256) void gate_gemm_act(
    const ushort_t* __restrict__ A, const ushort_t* __restrict__ B,
    ushort_t* __restrict__ dh) {
  constexpr int K = HID;
  __shared__ ushort_t As[128 * 32];  // 8 KB
  __shared__ ushort_t Bs[96 * 32];   // 6 KB

  const int tid = threadIdx.x;
  const int wave = tid >> 6;
  const int lane = tid & 63;
  const int quad = lane >> 4;
  const int l16 = lane & 15;

  const int m0 = blockIdx.x * 128;
  const int n0 = blockIdx.y * 96;
  const int wm = (wave & 1) * 64;
  const int wn = (wave >> 1) * 48;

  f32x4 acc[4][3] = {};

  const ushort_t* Ag = A + (size_t)m0 * K;
  const ushort_t* Bg = B + (size_t)n0 * K;

  for (int k0 = 0; k0 < K; k0 += 32) {
    // staging: A = 512 chunks (groups 0..7), B = 384 chunks (groups 8..13)
    for (int g = wave; g < 14; g += 4) {
      if (g < 8) {
        int cb = g * 64;
        int c = cb + lane;
        int row = c >> 2, kc = c & 3;
        load_lds16(Ag + (size_t)row * K + k0 + kc * 8, &As[cb * 8]);
      } else {
        int cb = (g - 8) * 64;
        int c = cb + lane;
        int row = c >> 2, kc = c & 3;
        load_lds16(Bg + (size_t)row * K + k0 + kc * 8, &Bs[cb * 8]);
      }
    }
    __syncthreads();

    bf16x8 af[4], bfr[3];
#pragma unroll
    for (int i = 0; i < 4; ++i)
      af[i] = *(const bf16x8*)&As[(wm + i * 16 + l16) * 32 + quad * 8];
#pragma unroll
    for (int j = 0; j < 3; ++j)
      bfr[j] = *(const bf16x8*)&Bs[(wn + j * 16 + l16) * 32 + quad * 8];
#pragma unroll
    for (int i = 0; i < 4; ++i)
#pragma unroll
      for (int j = 0; j < 3; ++j)
        acc[i][j] = __builtin_amdgcn_mfma_f32_16x16x32_bf16(af[i], bfr[j], acc[i][j], 0, 0, 0);
    __syncthreads();
  }

  // epilogue: C/D layout col=lane&15, row=quad*4+reg (m89-verified)
  const int hbase = (n0 + wn) / 3 + l16;  // n0+wn is a multiple of 48
#pragma unroll
  for (int i = 0; i < 4; ++i) {
    const int row = m0 + wm + i * 16 + quad * 4;
#pragma unroll
    for (int r = 0; r < 4; ++r) {
      float vi = acc[i][0][r];
      float vg = acc[i][1][r];
      float vo = acc[i][2][r];
      float si = 1.f / (1.f + expf(-vi));
      float tg = tanhf(vg);
      float so = 1.f / (1.f + expf(-vo));
      dh[(size_t)(row + r) * HID + hbase] = f2bf(so * tanhf(si * tg));
    }
  }
}

// ---------------------------------------------------------------------------
// Kernel B: C2 = dh @ WoutB^T  (16 rows x full 512 cols per block), then
// s = softmax(C2+bout); z += dt*s; zb = bf16(z); out[:,t+1] = softmax(z)·Wfc+bfc
// 256 blocks x 512 threads (8 waves; wave w covers cols w*64..w*64+63, FN=4)
// ---------------------------------------------------------------------------
__global__ __launch_bounds__(512) void gemm2_update(
    const ushort_t* __restrict__ dhp, const ushort_t* __restrict__ WoutB,
    const float* __restrict__ bout, float* __restrict__ z,
    ushort_t* __restrict__ zb, const float* __restrict__ Wfc,
    const float* __restrict__ bfc, const float* __restrict__ ts,
    float* __restrict__ out, int t) {
  constexpr int K = HID;
  __shared__ ushort_t As[16 * 32];    // 1 KB
  __shared__ ushort_t Bs[512 * 32];   // 32 KB
  __shared__ float red[2][8][16];     // cross-wave reduction scratch

  const int tid = threadIdx.x;
  const int wave = tid >> 6;
  const int lane = tid & 63;
  const int quad = lane >> 4;
  const int l16 = lane & 15;

  const int m0 = blockIdx.x * 16;
  const int wn = wave * 64;
  const int lr = quad * 4;  // local row base for this lane's quad

  f32x4 acc[4] = {};

  for (int k0 = 0; k0 < K; k0 += 32) {
    // A = 64 chunks (group 0), B = 2048 chunks (groups 1..32)
    for (int g = wave; g < 33; g += 8) {
      if (g == 0) {
        int row = lane >> 2, kc = lane & 3;
        load_lds16(dhp + (size_t)(m0 + row) * K + k0 + kc * 8, &As[0]);
      } else {
        int cb = (g - 1) * 64;
        int c = cb + lane;
        int row = c >> 2, kc = c & 3;
        load_lds16(WoutB + (size_t)row * K + k0 + kc * 8, &Bs[cb * 8]);
      }
    }
    __syncthreads();

    bf16x8 af = *(const bf16x8*)&As[l16 * 32 + quad * 8];
    bf16x8 bfr[4];
#pragma unroll
    for (int j = 0; j < 4; ++j)
      bfr[j] = *(const bf16x8*)&Bs[(wn + j * 16 + l16) * 32 + quad * 8];
#pragma unroll
    for (int j = 0; j < 4; ++j)
      acc[j] = __builtin_amdgcn_mfma_f32_16x16x32_bf16(af, bfr[j], acc[j], 0, 0, 0);
    __syncthreads();
  }

  const float dt = ts[t + 1] - ts[t];
  float bo[4], wfc[4];
#pragma unroll
  for (int j = 0; j < 4; ++j) {
    bo[j] = bout[wn + j * 16 + l16];
    wfc[j] = Wfc[wn + j * 16 + l16];
  }

  float lv[4][4];
#pragma unroll
  for (int j = 0; j < 4; ++j)
#pragma unroll
    for (int r = 0; r < 4; ++r) lv[j][r] = acc[j][r] + bo[j];

  // ---- softmax #1: row max over all 512 cols ----
  float pm[4];
#pragma unroll
  for (int r = 0; r < 4; ++r) {
    pm[r] = fmaxf(fmaxf(lv[0][r], lv[1][r]), fmaxf(lv[2][r], lv[3][r]));
#pragma unroll
    for (int off = 1; off < 16; off <<= 1) pm[r] = fmaxf(pm[r], __shfl_xor(pm[r], off));
  }
  if (l16 == 0) {
#pragma unroll
    for (int r = 0; r < 4; ++r) red[0][wave][lr + r] = pm[r];
  }
  __syncthreads();
  float mrow[4];
#pragma unroll
  for (int r = 0; r < 4; ++r) {
    mrow[r] = red[0][0][lr + r];
#pragma unroll
    for (int w = 1; w < 8; ++w) mrow[r] = fmaxf(mrow[r], red[0][w][lr + r]);
  }
  __syncthreads();

  // ---- softmax #1: exp + row sum ----
  float e1[4][4], ps[4];
#pragma unroll
  for (int r = 0; r < 4; ++r) {
    ps[r] = 0.f;
#pragma unroll
    for (int j = 0; j < 4; ++j) { e1[j][r] = expf(lv[j][r] - mrow[r]); ps[r] += e1[j][r]; }
#pragma unroll
    for (int off = 1; off < 16; off <<= 1) ps[r] += __shfl_xor(ps[r], off);
  }
  if (l16 == 0) {
#pragma unroll
    for (int r = 0; r < 4; ++r) red[0][wave][lr + r] = ps[r];
  }
  __syncthreads();
  float inv[4];
#pragma unroll
  for (int r = 0; r < 4; ++r) {
    float s = 0.f;
#pragma unroll
    for (int w = 0; w < 8; ++w) s += red[0][w][lr + r];
    inv[r] = 1.f / s;
  }
  __syncthreads();

  // ---- z update + bf16 recast ----
  float zn[4][4];
#pragma unroll
  for (int r = 0; r < 4; ++r) {
    const size_t base = (size_t)(m0 + lr + r) * HID;
#pragma unroll
    for (int j = 0; j < 4; ++j) {
      const size_t a = base + wn + j * 16 + l16;
      float v = z[a] + dt * e1[j][r] * inv[r];
      zn[j][r] = v;
      z[a] = v;
      zb[a] = f2bf(v);
    }
  }

  // ---- softmax #2 over zn + readout dot ----
  float pm2[4];
#pragma unroll
  for (int r = 0; r < 4; ++r) {
    pm2[r] = fmaxf(fmaxf(zn[0][r], zn[1][r]), fmaxf(zn[2][r], zn[3][r]));
#pragma unroll
    for (int off = 1; off < 16; off <<= 1) pm2[r] = fmaxf(pm2[r], __shfl_xor(pm2[r], off));
  }
  if (l16 == 0) {
#pragma unroll
    for (int r = 0; r < 4; ++r) red[0][wave][lr + r] = pm2[r];
  }
  __syncthreads();
  float mrow2[4];
#pragma unroll
  for (int r = 0; r < 4; ++r) {
    mrow2[r] = red[0][0][lr + r];
#pragma unroll
    for (int w = 1; w < 8; ++w) mrow2[r] = fmaxf(mrow2[r], red[0][w][lr + r]);
  }
  __syncthreads();

  float ps2[4], pd2[4];
#pragma unroll
  for (int r = 0; r < 4; ++r) {
    ps2[r] = 0.f; pd2[r] = 0.f;
#pragma unroll
    for (int j = 0; j < 4; ++j) {
      float e = expf(zn[j][r] - mrow2[r]);
      ps2[r] += e;
      pd2[r] += e * wfc[j];
    }
#pragma unroll
    for (int off = 1; off < 16; off <<= 1) {
      ps2[r] += __shfl_xor(ps2[r], off);
      pd2[r] += __shfl_xor(pd2[r], off);
    }
  }
  if (l16 == 0) {
#pragma unroll
    for (int r = 0; r < 4; ++r) { red[0][wave][lr + r] = ps2[r]; red[1][wave][lr + r] = pd2[r]; }
  }
  __syncthreads();
  if (wave == 0 && l16 == 0) {
#pragma unroll
    for (int r = 0; r < 4; ++r) {
      float s = 0.f, d = 0.f;
#pragma unroll
      for (int w = 0; w < 8; ++w) { s += red[0][w][lr + r]; d += red[1][w][lr + r]; }
      out[(size_t)(m0 + lr + r) * T_STEPS + t + 1] = d / s + bfc[0];
    }
  }
}

// ---------------------------------------------------------------------------
// weights fp32 -> bf16. Wcat2: packed/interleaved [1536,512]: packed row p:
// group=p/48, within=p%48, gate=within/16, hh=group*16+(within&15).
// WoutB: plain [512,512].
// ---------------------------------------------------------------------------
__global__ __launch_bounds__(256) void convw_kernel(
    const float* __restrict__ Wi, const float* __restrict__ Wg,
    const float* __restrict__ Wo, const float* __restrict__ Wout,
    ushort_t* __restrict__ Wcat2, ushort_t* __restrict__ WoutB) {
  const int t = blockIdx.x * 256 + threadIdx.x;  // 1024 blocks x 256 = 262144
  const float* src;
  ushort_t* dst;
  if (t < 196608) {  // Wcat2: 1536*512/4 elems-of-4
    int prow = t >> 7;
    int kk = (t & 127) * 4;
    int group = prow / 48;
    int within = prow % 48;
    int gate = within >> 4;
    int hh = group * 16 + (within & 15);
    src = (gate == 0 ? Wi : gate == 1 ? Wg : Wo) + (size_t)hh * HID + kk;
    dst = Wcat2 + (size_t)prow * HID + kk;
  } else {  // WoutB: 512*512/4
    int t2 = t - 196608;
    int row = t2 >> 7;
    int kk = (t2 & 127) * 4;
    src = Wout + (size_t)row * HID + kk;
    dst = WoutB + (size_t)row * HID + kk;
  }
  float4 v = *(const float4*)src;
  union { unsigned short us[4]; uint2 u; } p;
  p.us[0] = f2bf(v.x); p.us[1] = f2bf(v.y); p.us[2] = f2bf(v.z); p.us[3] = f2bf(v.w);
  *(uint2*)dst = p.u;
}

// z = y ; zb = bf16(y) ; out[:,0] = softmax(y)·Wfc + bfc   (one wave per row)
__global__ __launch_bounds__(256) void init_kernel(
    const float* __restrict__ y, float* __restrict__ z, ushort_t* __restrict__ zb,
    const float* __restrict__ Wfc, const float* __restrict__ bfc,
    float* __restrict__ out) {
  const int wave = threadIdx.x >> 6;
  const int lane = threadIdx.x & 63;
  const int row = blockIdx.x * 4 + wave;
  const float4* y4 = (const float4*)(y + (size_t)row * HID);
  float4 v0 = y4[lane * 2];
  float4 v1 = y4[lane * 2 + 1];
  float zn[8] = {v0.x, v0.y, v0.z, v0.w, v1.x, v1.y, v1.z, v1.w};
  float4* z4 = (float4*)(z + (size_t)row * HID);
  z4[lane * 2] = v0;
  z4[lane * 2 + 1] = v1;
  union { unsigned short us[8]; uint4 v; } p;
#pragma unroll
  for (int i = 0; i < 8; ++i) p.us[i] = f2bf(zn[i]);
  *(uint4*)(zb + (size_t)row * HID + lane * 8) = p.v;

  const float4* w4 = (const float4*)Wfc;
  float4 w0 = w4[lane * 2], w1 = w4[lane * 2 + 1];
  float w[8] = {w0.x, w0.y, w0.z, w0.w, w1.x, w1.y, w1.z, w1.w};
  float m = zn[0];
#pragma unroll
  for (int i = 1; i < 8; ++i) m = fmaxf(m, zn[i]);
  m = wave_max(m);
  float s = 0.f, d = 0.f;
#pragma unroll
  for (int i = 0; i < 8; ++i) { float e = expf(zn[i] - m); s += e; d += e * w[i]; }
  s = wave_sum(s);
  d = wave_sum(d);
  if (lane == 0) out[(size_t)row * T_STEPS] = d / s + bfc[0];
}

extern "C" void kernel_launch(void* const* d_in, const int* in_sizes, int n_in,
                              void* d_out, int out_size, void* d_ws, size_t ws_size,
                              hipStream_t stream) {
  const float* y    = (const float*)d_in[0];
  const float* ts   = (const float*)d_in[1];
  const float* Wi   = (const float*)d_in[2];
  // d_in[3] = Wf: computed-but-unused in reference -> skipped
  const float* Wg   = (const float*)d_in[4];
  const float* Wo   = (const float*)d_in[5];
  const float* Wout = (const float*)d_in[6];
  const float* bout = (const float*)d_in[7];
  const float* Wfc  = (const float*)d_in[8];
  const float* bfc  = (const float*)d_in[9];
  float* out = (float*)d_out;

  // workspace layout (bytes)
  char* ws = (char*)d_ws;
  float*    z     = (float*)(ws);                   // 4096*512*4  = 8388608
  ushort_t* zb    = (ushort_t*)(ws + 8388608);      // 4096*512*2  = 4194304
  ushort_t* dh    = (ushort_t*)(ws + 12582912);     // 4096*512*2  = 4194304
  ushort_t* Wcat2 = (ushort_t*)(ws + 16777216);     // 1536*512*2  = 1572864
  ushort_t* WoutB = (ushort_t*)(ws + 18350080);     // 512*512*2   = 524288
  // total 18,874,368 bytes

  convw_kernel<<<1024, 256, 0, stream>>>(Wi, Wg, Wo, Wout, Wcat2, WoutB);
  init_kernel<<<BATCH / 4, 256, 0, stream>>>(y, z, zb, Wfc, bfc, out);

  for (int t = 0; t < T_STEPS - 1; ++t) {
    gate_gemm_act<<<dim3(BATCH / 128, 1536 / 96), 256, 0, stream>>>(zb, Wcat2, dh);
    gemm2_update<<<256, 512, 0, stream>>>(dh, WoutB, bout, z, zb, Wfc, bfc, ts, out, t);
  }
}